// Round 3
// baseline (375.898 us; speedup 1.0000x reference)
//
#include <hip/hip_runtime.h>
#include <math.h>

#define TOPK 13
#define REG_MAX 16
#define EPSF 1e-7f
#define NEG_SENT -1e30f
#define NBCE 256
#define MAXG 32

// ---------------------------------------------------------------------------
// Mega kernel — 2 roles by blockIdx.x:
//   [0, B)        image role: one block per image. 4 waves; wave w owns gts
//                 w, w+4, ... Each wave computes the exact top-13 of
//                 align = sigmoid(score)*iou^6 over anchors inside its gt
//                 (analytic anchor grid, no anchor loads), packs winner keys
//                 into LDS. Then the whole block resolves per-anchor winners
//                 (argmax over gts) and computes all fg-gated loss terms,
//                 applying the per-image denom before writing ONE row of
//                 per-image contributions. fg never leaves the block.
//   [B, B+NBCE)   bce role: global zero-target BCE + sigmoid partial sums
//                 (per-block partials, no atomics, no memset).
//
// Packed key: bit62 valid | idx<<37 | float_bits(val)<<5 | (31-g).
// uint64 compare == (val, lower-g) order. Requires G<=32, N<2^25.
// ws_img[b*8 + k]: 0=npos 1=iou/den 2=dfl/(4den) 3=con/den 4=prob 5=corr 6=miou
// ---------------------------------------------------------------------------
__global__ __launch_bounds__(256) void mega_kernel(
    const float* __restrict__ boxes,    // (B,N,4)
    const float* __restrict__ scores,   // (B,N)
    const float* __restrict__ logits,   // (B,N,64)
    const float* __restrict__ prompt,   // (B,PD)
    const float* __restrict__ gts,      // (B,G,4)
    const int*   __restrict__ img_sz,
    float* __restrict__ ws_img,         // (B,8)
    float* __restrict__ ws_bce,         // (NBCE,2)
    int N, int B, int G, int PD, int total)
{
    const int tid  = threadIdx.x;
    const int lane = tid & 63;
    const int w    = tid >> 6;

    __shared__ float sval[256 * TOPK];
    __shared__ int   sidx[256 * TOPK];
    __shared__ unsigned long long pk[MAXG * TOPK];
    __shared__ float wred[4][7];

    if ((int)blockIdx.x >= B) {
        // ------------------ BCE role ------------------
        const int blk = blockIdx.x - B;
        float bce0 = 0.f, prsum = 0.f;
        const int nvec = total >> 2;
        const float4* s4 = (const float4*)scores;
        for (int n = blk*256 + tid; n < nvec; n += NBCE*256) {
            float4 v = s4[n];
            float ss[4] = { v.x, v.y, v.z, v.w };
#pragma unroll
            for (int q = 0; q < 4; q++) {
                float s = ss[q];
                bce0  += fmaxf(s, 0.0f) + log1pf(expf(-fabsf(s)));
                prsum += 1.0f / (1.0f + expf(-s));
            }
        }
        if (blk == 0) {
            for (int n = (nvec << 2) + tid; n < total; n += 256) {
                float s = scores[n];
                bce0  += fmaxf(s, 0.0f) + log1pf(expf(-fabsf(s)));
                prsum += 1.0f / (1.0f + expf(-s));
            }
        }
        float v1 = bce0, v2 = prsum;
#pragma unroll
        for (int off = 32; off > 0; off >>= 1) {
            v1 += __shfl_xor(v1, off);
            v2 += __shfl_xor(v2, off);
        }
        if (lane == 0) { wred[w][0] = v1; wred[w][1] = v2; }
        __syncthreads();
        if (tid == 0) {
            ws_bce[blk*2 + 0] = wred[0][0] + wred[1][0] + wred[2][0] + wred[3][0];
            ws_bce[blk*2 + 1] = wred[0][1] + wred[1][1] + wred[2][1] + wred[3][1];
        }
        return;
    }

    // ------------------ image role ------------------
    const int b   = blockIdx.x;
    const int img = img_sz[0];
    const int M   = G * TOPK;

    const float4* bx = (const float4*)(boxes + (size_t)b * N * 4);
    const float*  sc = scores + (size_t)b * N;

    // ---- per-gt exact top-13, one wave per gt ----
    for (int g = w; g < G; g += 4) {
        const float4 gt = ((const float4*)gts)[b*G + g];
        const float area_b = (gt.z - gt.x) * (gt.w - gt.y);

        float lv[TOPK];
        int   li[TOPK];
#pragma unroll
        for (int i = 0; i < TOPK; i++) { lv[i] = NEG_SENT; li[i] = 0; }

        int base = 0;
#pragma unroll
        for (int L = 0; L < 3; L++) {
            const int s = 8 << L;
            const int n = img / s;
            const float fs = (float)s;
            // candidate index rectangle (exact arithmetic: /pow2, -0.5 exact);
            // +-1 margin, actual coords re-tested (predicated) below.
            int i0 = max(0,     (int)ceilf (gt.x / fs - 0.5f) - 1);
            int i1 = min(n - 1, (int)floorf(gt.z / fs - 0.5f) + 1);
            int j0 = max(0,     (int)ceilf (gt.y / fs - 0.5f) - 1);
            int j1 = min(n - 1, (int)floorf(gt.w / fs - 0.5f) + 1);
            if (i1 >= i0 && j1 >= j0) {
                const int W = i1 - i0 + 1;
                const int cnt = W * (j1 - j0 + 1);
                // incremental row-carry instead of per-iter div/mod
                const int q64 = 64 / W, r64 = 64 - q64 * W;
                int ii = lane % W, jj = lane / W;
                for (int t = lane; t < cnt; t += 64) {
                    const int i = i0 + ii;
                    const int j = j0 + jj;
                    const int idx = base + j * n + i;
                    const float4 a    = bx[idx];
                    const float  sraw = sc[idx];
                    // analytic anchor coords — bit-identical to host table
                    const float ax = ((float)i + 0.5f) * fs;
                    const float ay = ((float)j + 0.5f) * fs;
                    float x1 = fmaxf(a.x, gt.x), y1 = fmaxf(a.y, gt.y);
                    float x2 = fminf(a.z, gt.z), y2 = fminf(a.w, gt.w);
                    float inter  = fmaxf(x2 - x1, 0.0f) * fmaxf(y2 - y1, 0.0f);
                    float area_a = (a.z - a.x) * (a.w - a.y);
                    float iou  = inter / (area_a + area_b - inter + EPSF);
                    float prob = 1.0f / (1.0f + expf(-sraw));
                    float i2v = iou * iou;
                    float align = prob * i2v * i2v * i2v;  // iou^6, ALPHA=1
                    bool inside = (ax >= gt.x) & (ax <= gt.z) & (ay >= gt.y) & (ay <= gt.w);
                    align = inside ? align : NEG_SENT;
                    if (align > lv[TOPK-1]) {
                        float cv = align; int ci = idx;
#pragma unroll
                        for (int q = 0; q < TOPK; q++) {
                            if (cv > lv[q]) {
                                float tv = lv[q]; int ti = li[q];
                                lv[q] = cv; li[q] = ci; cv = tv; ci = ti;
                            }
                        }
                    }
                    ii += r64; jj += q64;
                    if (ii >= W) { ii -= W; jj++; }
                }
            }
            base += n * n;
        }

        // spill sorted per-lane lists (dynamic head index needs memory)
#pragma unroll
        for (int i = 0; i < TOPK; i++) { sval[tid*TOPK+i] = lv[i]; sidx[tid*TOPK+i] = li[i]; }
        __builtin_amdgcn_s_waitcnt(0);   // lanes only read their OWN lists

        // wave-wide top-13 extraction -> packed keys straight into LDS
        int h = 0;
        for (int k = 0; k < TOPK; k++) {
            float v = (h < TOPK) ? sval[tid*TOPK + h] : NEG_SENT;
            float bv = v; int bs = lane;
#pragma unroll
            for (int off = 32; off > 0; off >>= 1) {
                float ov = __shfl_xor(bv, off);
                int   os = __shfl_xor(bs, off);
                if (ov > bv || (ov == bv && os < bs)) { bv = ov; bs = os; }
            }
            if (lane == bs) {
                unsigned long long p = 0ull;
                if (v >= 0.0f) {
                    p = (1ull << 62)
                      | ((unsigned long long)(unsigned int)sidx[tid*TOPK + h] << 37)
                      | ((unsigned long long)__float_as_uint(v) << 5)
                      | (unsigned long long)(31 - g);
                }
                pk[g*TOPK + k] = p;
                h++;
            }
        }
    }
    __syncthreads();

    // ---- winner resolution + fg losses, entry-per-thread ----
    float npos = 0.f, iouS = 0.f, dflS = 0.f, conS = 0.f;
    float probS = 0.f, corrS = 0.f, miouS = 0.f;

    const float imgf = fmaxf((float)img, 1.0f);
    float p0 = prompt[(size_t)b*PD + 0], p1 = prompt[(size_t)b*PD + 1];
    float pn = fmaxf(sqrtf(p0*p0 + p1*p1), 1e-12f);
    p0 /= pn; p1 /= pn;

    for (int e = tid; e < M; e += 256) {
        const unsigned long long mine = pk[e];
        if (mine == 0ull) continue;
        // lose iff another entry with the same idx-field has a larger key
        bool lose = false;
        for (int e2 = 0; e2 < M; e2++) {
            unsigned long long p2 = pk[e2];
            lose |= (((p2 ^ mine) >> 37) == 0ull) & (p2 > mine);
        }
        if (lose) continue;

        const int g   = e / TOPK;
        const int idx = (int)((mine >> 37) & 0x1FFFFFFull);
        const float4 tb = ((const float4*)gts)[b*G + g];

        // analytic level/anchor/stride from idx
        const int n0 = img >> 3, n1 = img >> 4;
        int r = idx; float fs; int n;
        if (r < n0*n0)              { fs = 8.0f;  n = n0; }
        else if (r < n0*n0 + n1*n1) { r -= n0*n0;         fs = 16.0f; n = n1; }
        else                        { r -= n0*n0 + n1*n1; fs = 32.0f; n = img >> 5; }
        const int jj = r / n, ii = r - jj * n;
        const float ax = ((float)ii + 0.5f) * fs;
        const float ay = ((float)jj + 0.5f) * fs;

        const float4 a = bx[idx];
        float s    = sc[idx];
        float prob = 1.0f / (1.0f + expf(-s));

        // overlap = iou(pred, gt)
        float x1 = fmaxf(a.x, tb.x), y1 = fmaxf(a.y, tb.y);
        float x2 = fminf(a.z, tb.z), y2 = fminf(a.w, tb.w);
        float inter  = fmaxf(x2 - x1, 0.f) * fmaxf(y2 - y1, 0.f);
        float area_a = (a.z - a.x) * (a.w - a.y);
        float area_b = (tb.z - tb.x) * (tb.w - tb.y);
        float iou = inter / (area_a + area_b - inter + EPSF);
        float tsc = fmaxf(iou, 0.1f);

        // CIoU
        float cw = fmaxf(a.z, tb.z) - fminf(a.x, tb.x);
        float ch = fmaxf(a.w, tb.w) - fminf(a.y, tb.y);
        float c2 = cw*cw + ch*ch + EPSF;
        float dxc = tb.x + tb.z - a.x - a.z;
        float dyc = tb.y + tb.w - a.y - a.w;
        float rho2 = (dxc*dxc + dyc*dyc) * 0.25f;
        float w1 = a.z - a.x, h1 = a.w - a.y + EPSF;
        float w2 = tb.z - tb.x, h2 = tb.w - tb.y + EPSF;
        float dat = atanf(w2/h2) - atanf(w1/h1);
        float v   = 0.4052847345693511f * dat * dat;   // 4/pi^2
        float alpha = v / (v - iou + (1.0f + EPSF));
        float ciou  = iou - rho2/c2 - v*alpha;
        iouS += 1.0f - ciou;

        // DFL — 4 sides x 16 logits (256B contiguous, 16B-aligned)
        float d4[4] = { (ax - tb.x)/fs, (ay - tb.y)/fs,
                        (tb.z - ax)/fs, (tb.w - ay)/fs };
        const float4* lg4 = (const float4*)(logits + ((size_t)b*N + idx) * (4*REG_MAX));
        float dfl_n = 0.f;
#pragma unroll
        for (int sd = 0; sd < 4; sd++) {
            float4 q0 = lg4[sd*4+0], q1 = lg4[sd*4+1], q2 = lg4[sd*4+2], q3 = lg4[sd*4+3];
            float row[REG_MAX] = { q0.x,q0.y,q0.z,q0.w, q1.x,q1.y,q1.z,q1.w,
                                   q2.x,q2.y,q2.z,q2.w, q3.x,q3.y,q3.z,q3.w };
            float d = fminf(fmaxf(d4[sd], 0.0f), (float)(REG_MAX-1) - 0.01f);
            int tl = (int)d;
            int tr = min(tl + 1, REG_MAX - 1);
            float wl = (float)tr - d;
            float wr = 1.0f - wl;
            float m = row[0];
#pragma unroll
            for (int jx = 1; jx < REG_MAX; jx++) m = fmaxf(m, row[jx]);
            float se = 0.f, rtl = row[0], rtr = row[0];
#pragma unroll
            for (int jx = 0; jx < REG_MAX; jx++) {
                se += expf(row[jx] - m);
                rtl = (jx == tl) ? row[jx] : rtl;   // static-index selects
                rtr = (jx == tr) ? row[jx] : rtr;
            }
            float lse = m + logf(se);
            dfl_n += (lse - rtl) * wl + (lse - rtr) * wr;
        }
        dflS += dfl_n;

        // contrast
        float cx = (tb.x + tb.z) * 0.5f / imgf;
        float cy = (tb.y + tb.w) * 0.5f / imgf;
        float cn = fmaxf(sqrtf(cx*cx + cy*cy), 1e-12f);
        conS += 1.0f - (cx*p0 + cy*p1) / cn;

        npos  += 1.0f;
        probS += prob;
        corrS += -s * tsc;
        miouS += iou;
    }

    // block reduce 7 values over 4 waves
    float vals[7] = { npos, iouS, dflS, conS, probS, corrS, miouS };
#pragma unroll
    for (int k = 0; k < 7; k++) {
        float v = vals[k];
#pragma unroll
        for (int off = 32; off > 0; off >>= 1) v += __shfl_xor(v, off);
        vals[k] = v;
    }
    if (lane == 0) {
#pragma unroll
        for (int k = 0; k < 7; k++) wred[w][k] = vals[k];
    }
    __syncthreads();
    if (tid == 0) {
        float fin[7];
#pragma unroll
        for (int k = 0; k < 7; k++)
            fin[k] = wred[0][k] + wred[1][k] + wred[2][k] + wred[3][k];
        float np    = fin[0];
        float denom = fmaxf(np, 1.0f);
        float* p = ws_img + (size_t)b * 8;
        p[0] = np;
        p[1] = fin[1] / denom;
        p[2] = fin[2] / (4.0f * denom);
        p[3] = fin[3] / denom;
        p[4] = fin[4];
        p[5] = fin[5];
        p[6] = fin[6];
    }
}

// ---------------------------------------------------------------------------
// Finalize: lanes 0..B-1 load their image's 7 contributions; all lanes
// strided-sum the NBCE bce partials; one butterfly; lane 0 writes 10 outputs.
// Fully deterministic.
// ---------------------------------------------------------------------------
__global__ __launch_bounds__(64) void finalize_kernel(
    const float* __restrict__ ws_img, const float* __restrict__ ws_bce,
    float* __restrict__ out, int N, int B)
{
    const int lane = threadIdx.x;
    float vals[9] = {0,0,0,0,0,0,0,0,0};
    if (lane < B) {
        const float* p = ws_img + (size_t)lane * 8;
#pragma unroll
        for (int k = 0; k < 7; k++) vals[k] = p[k];
    }
    for (int qb = lane; qb < NBCE; qb += 64) {
        vals[7] += ws_bce[2*qb + 0];
        vals[8] += ws_bce[2*qb + 1];
    }
#pragma unroll
    for (int k = 0; k < 9; k++) {
        float v = vals[k];
#pragma unroll
        for (int off = 32; off > 0; off >>= 1) v += __shfl_xor(v, off);
        vals[k] = v;
    }
    if (lane == 0) {
        float bce0 = vals[7], prall = vals[8];
        float match = (bce0 + vals[5]) / (float)N;   // sum_b match_loss_b
        float iou = vals[1], dfl = vals[2], con = vals[3];
        float tp  = vals[0];
        float tn  = (float)B * (float)N - tp;
        float nb  = (float)B;
        float loss = (1.0f*match + 7.5f*iou + 1.5f*dfl + 1.0f*con) / nb;
        float pd = fmaxf(tp, 1.0f), nd = fmaxf(tn, 1.0f);
        out[0] = loss;
        out[1] = match / nb;
        out[2] = iou / nb;
        out[3] = dfl / nb;
        out[4] = con / nb;
        out[5] = tp;
        out[6] = tn;
        out[7] = vals[4] / pd;
        out[8] = (prall - vals[4]) / nd;
        out[9] = vals[6] / pd;
    }
}

extern "C" void kernel_launch(void* const* d_in, const int* in_sizes, int n_in,
                              void* d_out, int out_size, void* d_ws, size_t ws_size,
                              hipStream_t stream)
{
    const float* boxes   = (const float*)d_in[0];
    const float* scores  = (const float*)d_in[1];
    const float* logits  = (const float*)d_in[4];
    const float* prompt  = (const float*)d_in[5];
    const float* gts     = (const float*)d_in[6];
    const int*   img     = (const int*)d_in[7];

    const int N  = in_sizes[2] / 2;
    const int B  = in_sizes[1] / N;
    const int G  = in_sizes[6] / (B * 4);
    const int PD = in_sizes[5] / B;

    float* out = (float*)d_out;
    char*  ws  = (char*)d_ws;

    float* ws_img = (float*)ws;                                // B*8 f32
    size_t off = ((size_t)B * 8 * sizeof(float) + 63) & ~(size_t)63;
    float* ws_bce = (float*)(ws + off);                        // NBCE*2 f32

    // every workspace word read below is freshly written each run -> no memset
    mega_kernel<<<B + NBCE, 256, 0, stream>>>(boxes, scores, logits, prompt,
                                              gts, img, ws_img, ws_bce,
                                              N, B, G, PD, B*N);
    finalize_kernel<<<1, 64, 0, stream>>>(ws_img, ws_bce, out, N, B);
}

// Round 5
// 247.328 us; speedup vs baseline: 1.5198x; 1.5198x over previous
//
#include <hip/hip_runtime.h>
#include <math.h>

#define TOPK 13
#define REG_MAX 16
#define EPSF 1e-7f
#define NEG_SENT -1e30f
#define NBCE 256
#define MAXM 512

// ---------------------------------------------------------------------------
// Single worker kernel, 2 roles by blockIdx.x (grid = B*G + NBCE):
//   [0, B*G)   topk role: one block (4 waves, 256 thr) per (b,g) — exact
//              top-13 of align = sigmoid(score)*iou^6 over anchors inside the
//              gt (analytic anchor grid, predicated inner loop, row-carry
//              index stepping). Packed keys go to global. The 20th (=G'th)
//              finisher for image b inherits the fg phase for that image:
//              winner resolution + all fg-gated losses + per-image denom,
//              one row out. Decoupled via cnt[b] (release fence + atomic).
//   [B*G, ...) bce role: global zero-target BCE + sigmoid partial sums.
// fg completers (B) and bce blocks (NBCE) bump cnt_done; the last block
// runs finalize inline (10 output scalars). Counters zeroed by a 256 B
// memset — the only other dispatch.
//
// Packed key: bit62 valid | idx<<37 | float_bits(val)<<5 | (31-g).
// uint64 compare == (val, lower-g) order. Requires G<=32, N<2^25.
// ---------------------------------------------------------------------------
__global__ __launch_bounds__(256) void worker_kernel(
    const float* __restrict__ boxes,    // (B,N,4)
    const float* __restrict__ scores,   // (B,N)
    const float* __restrict__ logits,   // (B,N,64)
    const float* __restrict__ prompt,   // (B,PD)
    const float* __restrict__ gts,      // (B,G,4)
    const int*   __restrict__ img_sz,
    int*   __restrict__ counters,       // [0..B-1]=cnt[b], [63]=cnt_done
    float* __restrict__ ws_img,         // (B,8) per-image contributions
    float* __restrict__ ws_bce,         // (NBCE,2)
    unsigned long long* __restrict__ pk_glob,  // (B*G,13)
    float* __restrict__ out,
    int N, int B, int G, int PD, int total)
{
    const int tid  = threadIdx.x;
    const int lane = tid & 63;
    const int w    = tid >> 6;
    const int NBG  = B * G;

    __shared__ float sval[256 * TOPK];
    __shared__ int   sidx[256 * TOPK];
    __shared__ float wtv[4][TOPK];
    __shared__ int   wti[4][TOPK];
    __shared__ unsigned long long pkL[MAXM];
    __shared__ float wred[4][7];
    __shared__ int flag_fg, flag_fin;

    bool do_finalize = false;

    if ((int)blockIdx.x >= NBG) {
        // ------------------ BCE role ------------------
        const int blk = blockIdx.x - NBG;
        float bce0 = 0.f, prsum = 0.f;
        const int nvec = total >> 2;
        const float4* s4 = (const float4*)scores;
        for (int n = blk*256 + tid; n < nvec; n += NBCE*256) {
            float4 v = s4[n];
            float ss[4] = { v.x, v.y, v.z, v.w };
#pragma unroll
            for (int q = 0; q < 4; q++) {
                float s = ss[q];
                bce0  += fmaxf(s, 0.0f) + log1pf(expf(-fabsf(s)));
                prsum += 1.0f / (1.0f + expf(-s));
            }
        }
        if (blk == 0) {
            for (int n = (nvec << 2) + tid; n < total; n += 256) {
                float s = scores[n];
                bce0  += fmaxf(s, 0.0f) + log1pf(expf(-fabsf(s)));
                prsum += 1.0f / (1.0f + expf(-s));
            }
        }
        float v1 = bce0, v2 = prsum;
#pragma unroll
        for (int off = 32; off > 0; off >>= 1) {
            v1 += __shfl_xor(v1, off);
            v2 += __shfl_xor(v2, off);
        }
        if (lane == 0) { wred[w][0] = v1; wred[w][1] = v2; }
        __syncthreads();
        if (tid == 0) {
            ws_bce[blk*2 + 0] = wred[0][0] + wred[1][0] + wred[2][0] + wred[3][0];
            ws_bce[blk*2 + 1] = wred[0][1] + wred[1][1] + wred[2][1] + wred[3][1];
            __threadfence();                              // release partials
            int d = atomicAdd(&counters[63], 1);
            flag_fin = (d == B + NBCE - 1);
        }
        __syncthreads();
        do_finalize = (flag_fin != 0);
    } else {
        // ------------------ topk role ------------------
        const int bg  = blockIdx.x;
        const int b   = bg / G;
        const int g   = bg - b * G;
        const int img = img_sz[0];
        const int M   = G * TOPK;

        const float4 gt = ((const float4*)gts)[bg];
        const float area_b = (gt.z - gt.x) * (gt.w - gt.y);

        float lv[TOPK];
        int   li[TOPK];
#pragma unroll
        for (int i = 0; i < TOPK; i++) { lv[i] = NEG_SENT; li[i] = 0; }

        const float4* bx = (const float4*)(boxes + (size_t)b * N * 4);
        const float*  sc = scores + (size_t)b * N;

        int base = 0;
#pragma unroll
        for (int L = 0; L < 3; L++) {
            const int s = 8 << L;
            const int n = img / s;
            const float fs = (float)s;
            // candidate rectangle (exact arithmetic: /pow2, -0.5 exact);
            // +-1 margin, actual coords re-tested (predicated) below.
            int i0 = max(0,     (int)ceilf (gt.x / fs - 0.5f) - 1);
            int i1 = min(n - 1, (int)floorf(gt.z / fs - 0.5f) + 1);
            int j0 = max(0,     (int)ceilf (gt.y / fs - 0.5f) - 1);
            int j1 = min(n - 1, (int)floorf(gt.w / fs - 0.5f) + 1);
            if (i1 >= i0 && j1 >= j0) {
                const int W = i1 - i0 + 1;
                const int cnt = W * (j1 - j0 + 1);
                const int q256 = 256 / W, r256 = 256 - q256 * W;
                int ii = tid % W, jj = tid / W;
                for (int t = tid; t < cnt; t += 256) {
                    const int i = i0 + ii;
                    const int j = j0 + jj;
                    const int idx = base + j * n + i;
                    const float4 a    = bx[idx];
                    const float  sraw = sc[idx];
                    // analytic anchor coords — bit-identical to host table
                    const float ax = ((float)i + 0.5f) * fs;
                    const float ay = ((float)j + 0.5f) * fs;
                    float x1 = fmaxf(a.x, gt.x), y1 = fmaxf(a.y, gt.y);
                    float x2 = fminf(a.z, gt.z), y2 = fminf(a.w, gt.w);
                    float inter  = fmaxf(x2 - x1, 0.0f) * fmaxf(y2 - y1, 0.0f);
                    float area_a = (a.z - a.x) * (a.w - a.y);
                    float iou  = inter / (area_a + area_b - inter + EPSF);
                    float prob = 1.0f / (1.0f + expf(-sraw));
                    float i2v = iou * iou;
                    float align = prob * i2v * i2v * i2v;   // iou^6, ALPHA=1
                    bool inside = (ax >= gt.x) & (ax <= gt.z) & (ay >= gt.y) & (ay <= gt.w);
                    align = inside ? align : NEG_SENT;
                    if (align > lv[TOPK-1]) {
                        float cv = align; int ci = idx;
#pragma unroll
                        for (int q = 0; q < TOPK; q++) {
                            if (cv > lv[q]) {
                                float tv = lv[q]; int ti = li[q];
                                lv[q] = cv; li[q] = ci; cv = tv; ci = ti;
                            }
                        }
                    }
                    ii += r256; jj += q256;
                    if (ii >= W) { ii -= W; jj++; }
                }
            }
            base += n * n;
        }

        // spill sorted per-lane lists (dynamic head index needs memory)
#pragma unroll
        for (int i = 0; i < TOPK; i++) { sval[tid*TOPK+i] = lv[i]; sidx[tid*TOPK+i] = li[i]; }
        __builtin_amdgcn_s_waitcnt(0);   // lanes only read their OWN lists

        // per-wave exact top-13 -> sorted list wtv[w][*]
        int h = 0;
        for (int k = 0; k < TOPK; k++) {
            float v = (h < TOPK) ? sval[tid*TOPK + h] : NEG_SENT;
            float bv = v; int bs = lane;
#pragma unroll
            for (int off = 32; off > 0; off >>= 1) {
                float ov = __shfl_xor(bv, off);
                int   os = __shfl_xor(bs, off);
                if (ov > bv || (ov == bv && os < bs)) { bv = ov; bs = os; }
            }
            if (lane == bs) {
                wtv[w][k] = v;
                wti[w][k] = sidx[tid*TOPK + h];
                h++;
            }
        }
        __syncthreads();

        // wave 0: 4-way merge of sorted lists, emit packed keys to global
        if (w == 0) {
            int hh = 0;
            for (int k = 0; k < TOPK; k++) {
                float v = (lane < 4) ? wtv[lane & 3][hh] : NEG_SENT;
                float bv = v; int bs = lane;
#pragma unroll
                for (int off = 32; off > 0; off >>= 1) {
                    float ov = __shfl_xor(bv, off);
                    int   os = __shfl_xor(bs, off);
                    if (ov > bv || (ov == bv && os < bs)) { bv = ov; bs = os; }
                }
                if (lane == bs) {
                    unsigned long long p = 0ull;
                    if (v >= 0.0f) {
                        p = (1ull << 62)
                          | ((unsigned long long)(unsigned int)wti[lane & 3][hh] << 37)
                          | ((unsigned long long)__float_as_uint(v) << 5)
                          | (unsigned long long)(31 - g);
                    }
                    pk_glob[bg*TOPK + k] = p;
                    hh++;
                }
            }
        }
        __syncthreads();   // all pk writes issued (barrier drains vmcnt)

        if (tid == 0) {
            __threadfence();                              // release keys
            int tc = atomicAdd(&counters[b], 1);
            flag_fg = (tc == G - 1);
        }
        __syncthreads();

        if (flag_fg) {
            // ---- this block inherited the fg phase for image b ----
            if (tid == 0) __threadfence();                // acquire keys
            __syncthreads();
            for (int e = tid; e < M; e += 256) pkL[e] = pk_glob[b*M + e];
            __syncthreads();

            float npos = 0.f, iouS = 0.f, dflS = 0.f, conS = 0.f;
            float probS = 0.f, corrS = 0.f, miouS = 0.f;

            const float imgf = fmaxf((float)img, 1.0f);
            float p0 = prompt[(size_t)b*PD + 0], p1 = prompt[(size_t)b*PD + 1];
            float pn = fmaxf(sqrtf(p0*p0 + p1*p1), 1e-12f);
            p0 /= pn; p1 /= pn;

            for (int e = tid; e < M; e += 256) {
                const unsigned long long mine = pkL[e];
                if (mine == 0ull) continue;
                bool lose = false;
                for (int e2 = 0; e2 < M; e2++) {
                    unsigned long long p2 = pkL[e2];
                    lose |= (((p2 ^ mine) >> 37) == 0ull) & (p2 > mine);
                }
                if (lose) continue;

                const int gg  = e / TOPK;
                const int idx = (int)((mine >> 37) & 0x1FFFFFFull);
                const float4 tb = ((const float4*)gts)[b*G + gg];

                // analytic level/anchor/stride from idx
                const int n0 = img >> 3, n1 = img >> 4;
                int r = idx; float fs; int n;
                if (r < n0*n0)              { fs = 8.0f;  n = n0; }
                else if (r < n0*n0 + n1*n1) { r -= n0*n0;         fs = 16.0f; n = n1; }
                else                        { r -= n0*n0 + n1*n1; fs = 32.0f; n = img >> 5; }
                const int jj = r / n, ii = r - jj * n;
                const float ax = ((float)ii + 0.5f) * fs;
                const float ay = ((float)jj + 0.5f) * fs;

                const float4 a = bx[idx];
                float s    = sc[idx];
                float prob = 1.0f / (1.0f + expf(-s));

                float x1 = fmaxf(a.x, tb.x), y1 = fmaxf(a.y, tb.y);
                float x2 = fminf(a.z, tb.z), y2 = fminf(a.w, tb.w);
                float inter  = fmaxf(x2 - x1, 0.f) * fmaxf(y2 - y1, 0.f);
                float area_a = (a.z - a.x) * (a.w - a.y);
                float area_g = (tb.z - tb.x) * (tb.w - tb.y);
                float iou = inter / (area_a + area_g - inter + EPSF);
                float tsc = fmaxf(iou, 0.1f);

                // CIoU
                float cw = fmaxf(a.z, tb.z) - fminf(a.x, tb.x);
                float ch = fmaxf(a.w, tb.w) - fminf(a.y, tb.y);
                float c2 = cw*cw + ch*ch + EPSF;
                float dxc = tb.x + tb.z - a.x - a.z;
                float dyc = tb.y + tb.w - a.y - a.w;
                float rho2 = (dxc*dxc + dyc*dyc) * 0.25f;
                float w1 = a.z - a.x, h1 = a.w - a.y + EPSF;
                float w2 = tb.z - tb.x, h2 = tb.w - tb.y + EPSF;
                float dat = atanf(w2/h2) - atanf(w1/h1);
                float v   = 0.4052847345693511f * dat * dat;   // 4/pi^2
                float alpha = v / (v - iou + (1.0f + EPSF));
                float ciou  = iou - rho2/c2 - v*alpha;
                iouS += 1.0f - ciou;

                // DFL — 4 sides x 16 logits (256B contiguous, 16B-aligned)
                float d4[4] = { (ax - tb.x)/fs, (ay - tb.y)/fs,
                                (tb.z - ax)/fs, (tb.w - ay)/fs };
                const float4* lg4 = (const float4*)(logits + ((size_t)b*N + idx) * (4*REG_MAX));
                float dfl_n = 0.f;
#pragma unroll
                for (int sd = 0; sd < 4; sd++) {
                    float4 q0 = lg4[sd*4+0], q1 = lg4[sd*4+1], q2 = lg4[sd*4+2], q3 = lg4[sd*4+3];
                    float row[REG_MAX] = { q0.x,q0.y,q0.z,q0.w, q1.x,q1.y,q1.z,q1.w,
                                           q2.x,q2.y,q2.z,q2.w, q3.x,q3.y,q3.z,q3.w };
                    float d = fminf(fmaxf(d4[sd], 0.0f), (float)(REG_MAX-1) - 0.01f);
                    int tl = (int)d;
                    int tr = min(tl + 1, REG_MAX - 1);
                    float wl = (float)tr - d;
                    float wr = 1.0f - wl;
                    float m = row[0];
#pragma unroll
                    for (int jx = 1; jx < REG_MAX; jx++) m = fmaxf(m, row[jx]);
                    float se = 0.f, rtl = row[0], rtr = row[0];
#pragma unroll
                    for (int jx = 0; jx < REG_MAX; jx++) {
                        se += expf(row[jx] - m);
                        rtl = (jx == tl) ? row[jx] : rtl;   // static-index selects
                        rtr = (jx == tr) ? row[jx] : rtr;
                    }
                    float lse = m + logf(se);
                    dfl_n += (lse - rtl) * wl + (lse - rtr) * wr;
                }
                dflS += dfl_n;

                // contrast
                float cx = (tb.x + tb.z) * 0.5f / imgf;
                float cy = (tb.y + tb.w) * 0.5f / imgf;
                float cn = fmaxf(sqrtf(cx*cx + cy*cy), 1e-12f);
                conS += 1.0f - (cx*p0 + cy*p1) / cn;

                npos  += 1.0f;
                probS += prob;
                corrS += -s * tsc;
                miouS += iou;
            }

            float vals[7] = { npos, iouS, dflS, conS, probS, corrS, miouS };
#pragma unroll
            for (int k = 0; k < 7; k++) {
                float v = vals[k];
#pragma unroll
                for (int off = 32; off > 0; off >>= 1) v += __shfl_xor(v, off);
                vals[k] = v;
            }
            if (lane == 0) {
#pragma unroll
                for (int k = 0; k < 7; k++) wred[w][k] = vals[k];
            }
            __syncthreads();
            if (tid == 0) {
                float fin[7];
#pragma unroll
                for (int k = 0; k < 7; k++)
                    fin[k] = wred[0][k] + wred[1][k] + wred[2][k] + wred[3][k];
                float np    = fin[0];
                float denom = fmaxf(np, 1.0f);
                float* p = ws_img + (size_t)b * 8;
                p[0] = np;
                p[1] = fin[1] / denom;
                p[2] = fin[2] / (4.0f * denom);
                p[3] = fin[3] / denom;
                p[4] = fin[4];
                p[5] = fin[5];
                p[6] = fin[6];
                __threadfence();                          // release image row
                int d = atomicAdd(&counters[63], 1);
                flag_fin = (d == B + NBCE - 1);
            }
            __syncthreads();
            do_finalize = (flag_fin != 0);
        }
    }

    // ---- last completer runs finalize inline ----
    if (do_finalize) {
        if (tid == 0) __threadfence();                    // acquire all rows
        __syncthreads();
        if (tid < 64) {
            const int ln = tid;
            float vals[9] = {0,0,0,0,0,0,0,0,0};
            if (ln < B) {
                const float* p = ws_img + (size_t)ln * 8;
#pragma unroll
                for (int k = 0; k < 7; k++) vals[k] = p[k];
            }
            for (int qb = ln; qb < NBCE; qb += 64) {
                vals[7] += ws_bce[2*qb + 0];
                vals[8] += ws_bce[2*qb + 1];
            }
#pragma unroll
            for (int k = 0; k < 9; k++) {
                float v = vals[k];
#pragma unroll
                for (int off = 32; off > 0; off >>= 1) v += __shfl_xor(v, off);
                vals[k] = v;
            }
            if (ln == 0) {
                float bce0 = vals[7], prall = vals[8];
                float match = (bce0 + vals[5]) / (float)N;
                float iou = vals[1], dfl = vals[2], con = vals[3];
                float tp  = vals[0];
                float tn  = (float)B * (float)N - tp;
                float nb  = (float)B;
                float loss = (1.0f*match + 7.5f*iou + 1.5f*dfl + 1.0f*con) / nb;
                float pd = fmaxf(tp, 1.0f), nd = fmaxf(tn, 1.0f);
                out[0] = loss;
                out[1] = match / nb;
                out[2] = iou / nb;
                out[3] = dfl / nb;
                out[4] = con / nb;
                out[5] = tp;
                out[6] = tn;
                out[7] = vals[4] / pd;
                out[8] = (prall - vals[4]) / nd;
                out[9] = vals[6] / pd;
            }
        }
    }
}

extern "C" void kernel_launch(void* const* d_in, const int* in_sizes, int n_in,
                              void* d_out, int out_size, void* d_ws, size_t ws_size,
                              hipStream_t stream)
{
    const float* boxes   = (const float*)d_in[0];
    const float* scores  = (const float*)d_in[1];
    const float* logits  = (const float*)d_in[4];
    const float* prompt  = (const float*)d_in[5];
    const float* gts     = (const float*)d_in[6];
    const int*   img     = (const int*)d_in[7];

    const int N  = in_sizes[2] / 2;
    const int B  = in_sizes[1] / N;
    const int G  = in_sizes[6] / (B * 4);
    const int PD = in_sizes[5] / B;
    const int NBG = B * G;

    float* out = (float*)d_out;
    char*  ws  = (char*)d_ws;

    int*   counters = (int*)ws;                            // 64 ints (256 B)
    float* ws_img   = (float*)(ws + 256);                  // B*8 f32
    size_t off = 256 + (((size_t)B * 8 * sizeof(float) + 63) & ~(size_t)63);
    float* ws_bce   = (float*)(ws + off);                  // NBCE*2 f32
    off += ((size_t)NBCE * 2 * sizeof(float) + 63) & ~(size_t)63;
    unsigned long long* pk = (unsigned long long*)(ws + off);  // NBG*13 u64

    hipMemsetAsync(counters, 0, 256, stream);
    worker_kernel<<<NBG + NBCE, 256, 0, stream>>>(boxes, scores, logits, prompt,
                                                  gts, img, counters, ws_img,
                                                  ws_bce, pk, out,
                                                  N, B, G, PD, B*N);
}

// Round 6
// 226.392 us; speedup vs baseline: 1.6604x; 1.0925x over previous
//
#include <hip/hip_runtime.h>
#include <math.h>

#define TOPK 13
#define REG_MAX 16
#define EPSF 1e-7f
#define MAXM 512
#define NEG_SENT -1e30f
#define NBCE 256

// ---------------------------------------------------------------------------
// Kernel 1 — fused (round-2 proven shape):
//   blocks [0, NBG)        : per (b,g) exact top-13 of align = sig(score)*iou^6
//   blocks [NBG, NBG+NBCE) : global zero-target BCE + sigmoid partial sums
// Independent roles overlap in one grid; per-block bce partials remove
// atomics and the zeroing memset. Candidate loop uses row-carry index
// stepping (one div per level, not per iteration).
//
// topk output is the PACKED winner key per slot:
//   bit62 valid | idx<<37 | float_bits(val)<<5 | (31-g)
// uint64 compare == (val, lower-g) order; idx field doubles as the
// "same anchor" discriminator in kernel 2. Requires G<=32, N<2^25.
// ---------------------------------------------------------------------------
__global__ __launch_bounds__(256) void k1_kernel(
    const float* __restrict__ boxes,    // (B,N,4)
    const float* __restrict__ scores,   // (B,N)
    const float* __restrict__ gts,      // (B,G,4)
    const int*   __restrict__ img_sz,
    unsigned long long* __restrict__ pk_out,   // (B*G, 13)
    float* __restrict__ bcepart,               // (NBCE, 2)
    int N, int G, int NBG, int total)
{
    const int tid  = threadIdx.x;
    const int lane = tid & 63;
    const int w    = tid >> 6;

    if ((int)blockIdx.x >= NBG) {
        // ------------------ BCE role ------------------
        const int blk = blockIdx.x - NBG;
        float bce0 = 0.f, prsum = 0.f;
        const int nvec = total >> 2;
        const float4* s4 = (const float4*)scores;
        for (int n = blk*256 + tid; n < nvec; n += NBCE*256) {
            float4 v = s4[n];
            float ss[4] = { v.x, v.y, v.z, v.w };
#pragma unroll
            for (int q = 0; q < 4; q++) {
                float s = ss[q];
                bce0  += fmaxf(s, 0.0f) + log1pf(expf(-fabsf(s)));
                prsum += 1.0f / (1.0f + expf(-s));
            }
        }
        if (blk == 0) {
            for (int n = (nvec << 2) + tid; n < total; n += 256) {
                float s = scores[n];
                bce0  += fmaxf(s, 0.0f) + log1pf(expf(-fabsf(s)));
                prsum += 1.0f / (1.0f + expf(-s));
            }
        }
        float v1 = bce0, v2 = prsum;
#pragma unroll
        for (int off = 32; off > 0; off >>= 1) {
            v1 += __shfl_xor(v1, off);
            v2 += __shfl_xor(v2, off);
        }
        __shared__ float r1[4], r2[4];
        if (lane == 0) { r1[w] = v1; r2[w] = v2; }
        __syncthreads();
        if (tid == 0) {
            bcepart[blk*2 + 0] = r1[0] + r1[1] + r1[2] + r1[3];
            bcepart[blk*2 + 1] = r2[0] + r2[1] + r2[2] + r2[3];
        }
        return;
    }

    // ------------------ top-k role ------------------
    const int bg  = blockIdx.x;
    const int b   = bg / G;
    const int g   = bg - b * G;
    const int img = img_sz[0];

    const float4 gt = ((const float4*)gts)[bg];
    const float area_b = (gt.z - gt.x) * (gt.w - gt.y);

    float lv[TOPK];
    int   li[TOPK];
#pragma unroll
    for (int i = 0; i < TOPK; i++) { lv[i] = NEG_SENT; li[i] = 0; }

    const float4* bx = (const float4*)(boxes + (size_t)b * N * 4);
    const float*  sc = scores + (size_t)b * N;

    int base = 0;
#pragma unroll
    for (int L = 0; L < 3; L++) {
        const int s = 8 << L;
        const int n = img / s;
        const float fs = (float)s;
        // candidate index rectangle (exact arithmetic: /pow2 and -0.5 exact);
        // +-1 margin, actual coords re-tested (predicated) below.
        int i0 = max(0,     (int)ceilf (gt.x / fs - 0.5f) - 1);
        int i1 = min(n - 1, (int)floorf(gt.z / fs - 0.5f) + 1);
        int j0 = max(0,     (int)ceilf (gt.y / fs - 0.5f) - 1);
        int j1 = min(n - 1, (int)floorf(gt.w / fs - 0.5f) + 1);
        if (i1 >= i0 && j1 >= j0) {
            const int W = i1 - i0 + 1;
            const int cnt = W * (j1 - j0 + 1);
            // row-carry stepping: one div per level instead of per iteration
            const int q256 = 256 / W, r256 = 256 - q256 * W;
            int ii = tid % W, jj = tid / W;
            for (int t = tid; t < cnt; t += 256) {
                const int i = i0 + ii;
                const int j = j0 + jj;
                const int idx = base + j * n + i;
                // unconditional loads -> pipelined across the predicate
                const float4 a    = bx[idx];
                const float  sraw = sc[idx];
                // analytic anchor coords — bit-identical to the host table
                const float ax = ((float)i + 0.5f) * fs;
                const float ay = ((float)j + 0.5f) * fs;
                float x1 = fmaxf(a.x, gt.x), y1 = fmaxf(a.y, gt.y);
                float x2 = fminf(a.z, gt.z), y2 = fminf(a.w, gt.w);
                float inter  = fmaxf(x2 - x1, 0.0f) * fmaxf(y2 - y1, 0.0f);
                float area_a = (a.z - a.x) * (a.w - a.y);
                float iou  = inter / (area_a + area_b - inter + EPSF);
                float prob = 1.0f / (1.0f + expf(-sraw));
                float i2 = iou * iou;
                float align = prob * i2 * i2 * i2;   // iou^6 (BETA=6), ALPHA=1
                bool inside = (ax >= gt.x) & (ax <= gt.z) & (ay >= gt.y) & (ay <= gt.w);
                align = inside ? align : NEG_SENT;
                if (align > lv[TOPK-1]) {
                    float cv = align; int ci = idx;
#pragma unroll
                    for (int q = 0; q < TOPK; q++) {
                        if (cv > lv[q]) {
                            float tv = lv[q]; int ti = li[q];
                            lv[q] = cv; li[q] = ci; cv = tv; ci = ti;
                        }
                    }
                }
                ii += r256; jj += q256;
                if (ii >= W) { ii -= W; jj++; }
            }
        }
        base += n * n;
    }

    // spill sorted per-lane lists to LDS (dynamic head index needs memory)
    __shared__ float sval[256 * TOPK];
    __shared__ int   sidx[256 * TOPK];
#pragma unroll
    for (int i = 0; i < TOPK; i++) { sval[tid*TOPK+i] = lv[i]; sidx[tid*TOPK+i] = li[i]; }
    __builtin_amdgcn_s_waitcnt(0);   // lanes only read their OWN lists below

    // per-wave exact top-13 -> sorted list wtv[w][*]
    __shared__ float wtv[4][TOPK];
    __shared__ int   wti[4][TOPK];
    int h = 0;
    for (int k = 0; k < TOPK; k++) {
        float v = (h < TOPK) ? sval[tid*TOPK + h] : NEG_SENT;
        float bv = v; int bs = lane;
#pragma unroll
        for (int off = 32; off > 0; off >>= 1) {
            float ov = __shfl_xor(bv, off);
            int   os = __shfl_xor(bs, off);
            if (ov > bv || (ov == bv && os < bs)) { bv = ov; bs = os; }
        }
        if (lane == bs) {
            wtv[w][k] = v;
            wti[w][k] = sidx[tid*TOPK + h];
            h++;
        }
    }
    __syncthreads();

    // wave 0: 4-way merge of sorted lists, emit packed keys
    if (w == 0) {
        int hh = 0;
        for (int k = 0; k < TOPK; k++) {
            float v = (lane < 4) ? wtv[lane & 3][hh] : NEG_SENT;
            float bv = v; int bs = lane;
#pragma unroll
            for (int off = 32; off > 0; off >>= 1) {
                float ov = __shfl_xor(bv, off);
                int   os = __shfl_xor(bs, off);
                if (ov > bv || (ov == bv && os < bs)) { bv = ov; bs = os; }
            }
            if (lane == bs) {
                unsigned long long p = 0ull;
                if (v >= 0.0f) {
                    p = (1ull << 62)
                      | ((unsigned long long)(unsigned int)wti[lane & 3][hh] << 37)
                      | ((unsigned long long)__float_as_uint(v) << 5)
                      | (unsigned long long)(31 - g);
                }
                pk_out[bg*TOPK + k] = p;
                hh++;
            }
        }
    }
}

// ---------------------------------------------------------------------------
// Kernel 2: one wave per (b,g). 4 lanes per top-k entry: winner scan strided
// x4 (65 iters instead of 260), DFL one side per lane. Anchor coords and
// stride recovered analytically from idx (no anchors/strides loads).
// part[bg*7 + k]: 0=npos 1=iou 2=dfl 3=con 4=prob 5=corr(-s*t) 6=miou
// ---------------------------------------------------------------------------
__global__ __launch_bounds__(64) void fg_kernel(
    const float* __restrict__ boxes, const float* __restrict__ scores,
    const float* __restrict__ logits, const float* __restrict__ prompt,
    const float* __restrict__ gts, const int* __restrict__ img_sz,
    const unsigned long long* __restrict__ pk_in,
    float* __restrict__ part, int N, int G, int PD)
{
    const int bg   = blockIdx.x;
    const int b    = bg / G;
    const int g    = bg - b * G;
    const int lane = threadIdx.x;
    const int M    = G * TOPK;   // 260 for the graded shape

    __shared__ unsigned long long pk[MAXM];
    for (int e = lane; e < M; e += 64) pk[e] = pk_in[b*M + e];
    __builtin_amdgcn_s_waitcnt(0);   // single wave: drain LDS writes

    const int ent = lane >> 2;       // entry 0..15 (13 real)
    const int q   = lane & 3;        // sub-lane within entry group
    unsigned long long mine = 0ull;
    if (ent < TOPK) mine = pk[g*TOPK + ent];

    int lose = 0;
    if (mine != 0ull) {
        // lose iff another entry with the same idx-field has a larger key
        for (int e2 = q; e2 < M; e2 += 4) {
            unsigned long long p2 = pk[e2];
            lose |= (int)((((p2 ^ mine) >> 37) == 0ull) & (p2 > mine));
        }
    }
    lose |= __shfl_xor(lose, 1);
    lose |= __shfl_xor(lose, 2);
    const bool winner = (mine != 0ull) && (lose == 0);

    const float4 tb = ((const float4*)gts)[b*G + g];
    const int img = img_sz[0];

    float side = 0.f;
    float npos = 0.f, iouv = 0.f, conv = 0.f, probv = 0.f, corrv = 0.f, miouv = 0.f;

    if (winner) {
        const int idx = (int)((mine >> 37) & 0x1FFFFFFull);
        // analytic level/anchor/stride from idx
        const int n0 = img >> 3, n1 = img >> 4, n2 = img >> 5;
        int r = idx; float fs; int n;
        if (r < n0*n0)                 { fs = 8.0f;  n = n0; }
        else if (r < n0*n0 + n1*n1)    { r -= n0*n0;         fs = 16.0f; n = n1; }
        else                           { r -= n0*n0 + n1*n1; fs = 32.0f; n = n2; }
        (void)n2;
        const int jj = r / n, ii = r - jj * n;
        const float ax = ((float)ii + 0.5f) * fs;
        const float ay = ((float)jj + 0.5f) * fs;

        // DFL — this lane handles side q (16 logits, 4x float4, contiguous)
        float dq = (q == 0) ? (ax - tb.x) : (q == 1) ? (ay - tb.y)
                 : (q == 2) ? (tb.z - ax) : (tb.w - ay);
        dq /= fs;
        const float4* lg4 = (const float4*)(logits + ((size_t)b*N + idx) * (4*REG_MAX)) + q*4;
        float4 q0 = lg4[0], q1 = lg4[1], q2 = lg4[2], q3 = lg4[3];
        float row[REG_MAX] = { q0.x,q0.y,q0.z,q0.w, q1.x,q1.y,q1.z,q1.w,
                               q2.x,q2.y,q2.z,q2.w, q3.x,q3.y,q3.z,q3.w };
        float d = fminf(fmaxf(dq, 0.0f), (float)(REG_MAX-1) - 0.01f);
        int tl = (int)d;
        int tr = min(tl + 1, REG_MAX - 1);
        float wl = (float)tr - d;
        float wr = 1.0f - wl;
        float m = row[0];
#pragma unroll
        for (int jx = 1; jx < REG_MAX; jx++) m = fmaxf(m, row[jx]);
        float se = 0.f, rtl = row[0], rtr = row[0];
#pragma unroll
        for (int jx = 0; jx < REG_MAX; jx++) {
            se += expf(row[jx] - m);
            rtl = (jx == tl) ? row[jx] : rtl;   // static-index selects, no scratch
            rtr = (jx == tr) ? row[jx] : rtr;
        }
        float lse = m + logf(se);
        side = (lse - rtl) * wl + (lse - rtr) * wr;
    }
    // sum the 4 sides within the entry group (butterfly; all lanes uniform)
    float dfl4 = side;
    dfl4 += __shfl_xor(dfl4, 1);
    dfl4 += __shfl_xor(dfl4, 2);

    float dflv = 0.f;
    if (winner && q == 0) {
        const int idx = (int)((mine >> 37) & 0x1FFFFFFull);
        const float4 a = ((const float4*)(boxes + (size_t)b*N*4))[idx];
        float s    = scores[(size_t)b*N + idx];
        float prob = 1.0f / (1.0f + expf(-s));

        // overlap = iou(pred, gt)
        float x1 = fmaxf(a.x, tb.x), y1 = fmaxf(a.y, tb.y);
        float x2 = fminf(a.z, tb.z), y2 = fminf(a.w, tb.w);
        float inter  = fmaxf(x2 - x1, 0.f) * fmaxf(y2 - y1, 0.f);
        float area_a = (a.z - a.x) * (a.w - a.y);
        float area_b = (tb.z - tb.x) * (tb.w - tb.y);
        float iou = inter / (area_a + area_b - inter + EPSF);
        float tsc = fmaxf(iou, 0.1f);

        // CIoU
        float cw = fmaxf(a.z, tb.z) - fminf(a.x, tb.x);
        float ch = fmaxf(a.w, tb.w) - fminf(a.y, tb.y);
        float c2 = cw*cw + ch*ch + EPSF;
        float dxc = tb.x + tb.z - a.x - a.z;
        float dyc = tb.y + tb.w - a.y - a.w;
        float rho2 = (dxc*dxc + dyc*dyc) * 0.25f;
        float w1 = a.z - a.x, h1 = a.w - a.y + EPSF;
        float w2 = tb.z - tb.x, h2 = tb.w - tb.y + EPSF;
        float dat = atanf(w2/h2) - atanf(w1/h1);
        float v   = 0.4052847345693511f * dat * dat;   // 4/pi^2
        float alpha = v / (v - iou + (1.0f + EPSF));
        float ciou  = iou - rho2/c2 - v*alpha;
        iouv = 1.0f - ciou;
        dflv = dfl4;

        // contrast
        float imgf = fmaxf((float)img, 1.0f);
        float p0 = prompt[(size_t)b*PD + 0], p1 = prompt[(size_t)b*PD + 1];
        float pn = fmaxf(sqrtf(p0*p0 + p1*p1), 1e-12f);
        float cx = (tb.x + tb.z) * 0.5f / imgf;
        float cy = (tb.y + tb.w) * 0.5f / imgf;
        float cn = fmaxf(sqrtf(cx*cx + cy*cy), 1e-12f);
        conv = 1.0f - (cx*(p0/pn) + cy*(p1/pn)) / cn;

        npos  = 1.0f;
        probv = prob;
        corrv = -s * tsc;
        miouv = iou;
    }

    // butterfly sum across the wave, lane 0 stores the 7 partials
    float vals[7] = { npos, iouv, dflv, conv, probv, corrv, miouv };
#pragma unroll
    for (int k = 0; k < 7; k++) {
        float v = vals[k];
#pragma unroll
        for (int off = 32; off > 0; off >>= 1) v += __shfl_xor(v, off);
        vals[k] = v;
    }
    if (lane == 0) {
        float* p = part + (size_t)bg * 7;
#pragma unroll
        for (int k = 0; k < 7; k++) p[k] = vals[k];
    }
}

// ---------------------------------------------------------------------------
// Finalize: lanes 0..B-1 each sum their image's G partials in fixed order and
// apply the per-image denom; all lanes strided-sum the NBCE bce partials;
// one butterfly combine; lane 0 writes the 10 outputs. Fully deterministic.
// ---------------------------------------------------------------------------
__global__ __launch_bounds__(64) void finalize_kernel(
    const float* __restrict__ part, const float* __restrict__ bcepart,
    float* __restrict__ out, int N, int B, int G)
{
    const int lane = threadIdx.x;
    float np = 0.f, iouS = 0.f, dflS = 0.f, conS = 0.f;
    float probS = 0.f, corrS = 0.f, miouS = 0.f;
    if (lane < B) {
        float a0=0,a1=0,a2=0,a3=0,a4=0,a5=0,a6=0;
        const float* p = part + (size_t)lane * G * 7;
        for (int g = 0; g < G; g++) {
            a0 += p[g*7+0]; a1 += p[g*7+1]; a2 += p[g*7+2]; a3 += p[g*7+3];
            a4 += p[g*7+4]; a5 += p[g*7+5]; a6 += p[g*7+6];
        }
        float denom = fmaxf(a0, 1.0f);
        np    = a0;
        iouS  = a1 / denom;
        dflS  = a2 / (4.0f * denom);
        conS  = a3 / denom;
        probS = a4;
        corrS = a5;
        miouS = a6;
    }
    float b0 = 0.f, b1 = 0.f;
    for (int qb = lane; qb < NBCE; qb += 64) {
        b0 += bcepart[2*qb + 0];
        b1 += bcepart[2*qb + 1];
    }
    float vals[9] = { np, iouS, dflS, conS, probS, corrS, miouS, b0, b1 };
#pragma unroll
    for (int k = 0; k < 9; k++) {
        float v = vals[k];
#pragma unroll
        for (int off = 32; off > 0; off >>= 1) v += __shfl_xor(v, off);
        vals[k] = v;
    }
    if (lane == 0) {
        float bce0 = vals[7], prall = vals[8];
        float match = (bce0 + vals[5]) / (float)N;   // sum_b match_loss_b
        float iou = vals[1], dfl = vals[2], con = vals[3];
        float tp  = vals[0];
        float tn  = (float)B * (float)N - tp;
        float nb  = (float)B;
        float loss = (1.0f*match + 7.5f*iou + 1.5f*dfl + 1.0f*con) / nb;
        float pd = fmaxf(tp, 1.0f), nd = fmaxf(tn, 1.0f);
        out[0] = loss;
        out[1] = match / nb;
        out[2] = iou / nb;
        out[3] = dfl / nb;
        out[4] = con / nb;
        out[5] = tp;
        out[6] = tn;
        out[7] = vals[4] / pd;
        out[8] = (prall - vals[4]) / nd;
        out[9] = vals[6] / pd;
    }
}

extern "C" void kernel_launch(void* const* d_in, const int* in_sizes, int n_in,
                              void* d_out, int out_size, void* d_ws, size_t ws_size,
                              hipStream_t stream)
{
    const float* boxes   = (const float*)d_in[0];
    const float* scores  = (const float*)d_in[1];
    const float* logits  = (const float*)d_in[4];
    const float* prompt  = (const float*)d_in[5];
    const float* gts     = (const float*)d_in[6];
    const int*   img     = (const int*)d_in[7];

    const int N  = in_sizes[2] / 2;
    const int B  = in_sizes[1] / N;
    const int G  = in_sizes[6] / (B * 4);
    const int PD = in_sizes[5] / B;
    const int NBG = B * G;

    float* out = (float*)d_out;
    char*  ws  = (char*)d_ws;

    unsigned long long* pk = (unsigned long long*)ws;          // NBG*13 u64
    size_t off = (size_t)NBG * TOPK * sizeof(unsigned long long);
    off = (off + 63) & ~(size_t)63;
    float* part = (float*)(ws + off);                          // NBG*7 f32
    off += (size_t)NBG * 7 * sizeof(float);
    off = (off + 63) & ~(size_t)63;
    float* bcep = (float*)(ws + off);                          // NBCE*2 f32

    // every workspace word read below is freshly written each run -> no memset
    k1_kernel<<<NBG + NBCE, 256, 0, stream>>>(boxes, scores, gts, img,
                                              pk, bcep, N, G, NBG, B*N);
    fg_kernel<<<NBG, 64, 0, stream>>>(boxes, scores, logits, prompt,
                                      gts, img, pk, part, N, G, PD);
    finalize_kernel<<<1, 64, 0, stream>>>(part, bcep, out, N, B, G);
}